// Round 18
// baseline (577.495 us; speedup 1.0000x reference)
//
#include <hip/hip_runtime.h>

// VQ codebook assignment via merged single-accumulator split-f16 MFMA GEMM (K=768 effective).
// R18 = R15 (135us champion) + merge/gather FUSED into vqmm via decoupled last-arriver
// (threadfence + per-by atomic counter; 32nd block merges its 256 tokens). Removes the
// third kernel launch and overlaps the 34MB quantize write with remaining GEMM compute.
// XCD swizzle makes the merger's cv/ci reads L2-local (all 32 bx-blocks of a by share XCD).
//   x:       [B=32, C=256, H=32, W=32] f32   -> tokens [32768][256]
//   embed_w: [K=2048, C=256] f32
// out f32: quantize [32,256,32,32] (8388608) | embed_index [32,32,32] (32768 as float) | loss [1]=0
//
// Math (verified R11-R17): xh=f16(64x), xl=f16(64x-xh); eh=f16(2^15 e), el=f16(2^15 e - eh).
//   acc = sum xh*eh + xh*el + xl*eh == 2^21*dot - sum(xl*el)  (dropped ~1e-6 rel)
//   d = 2^21*esq - 2*acc ; argmin preserved.
// Register law: 3 waves/SIMD => <=170/wave; ~150 used. Tripwires: VGPR_Count, FETCH bloat.
// Determinism: merging block varies run-to-run but merged RESULT is deterministic.
// cnt[128] zeroed by prep every launch (stream-ordered) -> graph-replay safe.

#define CDIM 256
#define KDIM 2048
#define HW   1024
#define NTOK 32768
#define QOFF 8388608
#define LOFF (QOFF + NTOK)

typedef _Float16 f16x8 __attribute__((ext_vector_type(8)));
typedef float    f32x4 __attribute__((ext_vector_type(4)));

__device__ __forceinline__ f16x8 ld16(const char* p) { return *(const f16x8*)(p); }

// ---------------- fused prep: blocks 0..1023 = X transpose, 1024..1279 = E limbs ----------------
__global__ __launch_bounds__(256) void prep_kernel(const float* __restrict__ x,
                                                   const float* __restrict__ ew,
                                                   char* __restrict__ Aws,
                                                   char* __restrict__ Ews,
                                                   float* __restrict__ esq,
                                                   int* __restrict__ cnt,
                                                   float* __restrict__ out) {
    __shared__ float tile[32][257];
    const int t = threadIdx.x;
    if (blockIdx.x < 1024) {
        const int bid = blockIdx.x;              // 32 b * 8 kc * 4 hwblk
        const int b = bid >> 5;
        const int kc = (bid >> 2) & 7;
        const int c0 = kc * 32;
        const int hw0 = (bid & 3) * 256;
        #pragma unroll 8
        for (int r = 0; r < 32; ++r)
            tile[r][t] = x[((size_t)(b * CDIM + c0 + r) << 10) + hw0 + t];
        __syncthreads();
        union { _Float16 h[32]; uint4 q[4]; } Hb, Lb;
        #pragma unroll 8
        for (int r = 0; r < 32; ++r) {
            const float xs = tile[r][t] * 64.0f;
            const _Float16 hh = (_Float16)xs;
            Hb.h[r] = hh;
            Lb.h[r] = (_Float16)(xs - (float)hh);
        }
        const int tok = b * HW + hw0 + t;
        const int p = tok >> 6, row = tok & 63;
        char* d = Aws + (size_t)p * 65536 + kc * 8192 + row * 16;
        #pragma unroll
        for (int g = 0; g < 4; ++g) {
            *(uint4*)(d + g * 1024)        = Hb.q[g];   // high limb
            *(uint4*)(d + 4096 + g * 1024) = Lb.q[g];   // low limb
        }
    } else {
        const int bid = blockIdx.x - 1024;             // 256 blocks x 8 codes
        const int code = bid * 8 + (t >> 5);
        const int u = t & 31;
        const float4 v0 = *(const float4*)&ew[(size_t)code * CDIM + u * 8];
        const float4 v1 = *(const float4*)&ew[(size_t)code * CDIM + u * 8 + 4];
        float s = v0.x*v0.x + v0.y*v0.y + v0.z*v0.z + v0.w*v0.w
                + v1.x*v1.x + v1.y*v1.y + v1.z*v1.z + v1.w*v1.w;
        #pragma unroll
        for (int m = 16; m >= 1; m >>= 1) s += __shfl_xor(s, m, 32);
        if (u == 0) esq[code] = s * 2097152.0f;        // 2^21 * esq
        const float e[8] = {v0.x, v0.y, v0.z, v0.w, v1.x, v1.y, v1.z, v1.w};
        union { _Float16 h[8]; uint4 q; } H, L;
        #pragma unroll
        for (int j = 0; j < 8; ++j) {
            const float ev = e[j] * 32768.0f;          // 2^15 * e
            const _Float16 hh = (_Float16)ev;
            H.h[j] = hh;
            L.h[j] = (_Float16)(ev - (float)hh);
        }
        const int kc = u >> 2, g = u & 3;
        const int p = code >> 6, row = code & 63;
        char* d = Ews + (size_t)p * 65536 + kc * 8192 + g * 1024 + row * 16;
        *(uint4*)d = H.q;
        *(uint4*)(d + 4096) = L.q;
        if (bid == 0 && t < 128) cnt[t] = 0;           // reset merge counters each launch
        if (bid == 0 && t == 0) out[LOFF] = 0.0f;
    }
}

// ---------------- fused MFMA GEMM + argmin + last-arriver merge/gather ----------------
// Block = 4 waves x 64 tokens (256 tokens) over ONE shared 64-code panel, quarter-dbuf LDS-E.
__global__ __launch_bounds__(256, 3) void vqmm_kernel(const char* __restrict__ Aws,
                                                      const char* __restrict__ Ews,
                                                      const float* __restrict__ esq,
                                                      float* __restrict__ cv,
                                                      int* __restrict__ ci,
                                                      int* __restrict__ cnt,
                                                      const float* __restrict__ ew,
                                                      float* __restrict__ out) {
    __shared__ __align__(16) char elds[32768];   // buf0 | buf1 (16KB each = 2 kc chunks)
    __shared__ int sIdx256[256];
    __shared__ int lastFlag;

    const int t = threadIdx.x;
    const int bid = blockIdx.x;                     // 4096 blocks
    // bijective XCD-grouped swizzle: the 32 code-panels of one token-group share bid%8
    const int by = (bid & 7) | ((bid >> 8) << 3);   // token group 0..127 (256 tokens)
    const int bx = (bid >> 3) & 31;                 // code panel 0..31   (64 codes)
    const int lane = t & 63, w = t >> 6;
    const int g = lane >> 4, lr = lane & 15;
    const int r = (bid + w) & 1;                    // intra-quarter rotation (anti-lockstep)

    const char* pa = Aws + (size_t)(by * 4 + w) * 65536 + g * 1024 + lr * 16;
    const char* esrc = Ews + (size_t)bx * 65536;

    f16x8 fa[4], fb[4], ec[4], ed[4];
    uint4 rg[4];

    // prologue: stage quarter 0 -> buf0; A frags for first phase (kc = r)
    #pragma unroll
    for (int j = 0; j < 4; ++j)
        rg[j] = *(const uint4*)(esrc + j * 4096 + t * 16);
    {
        const char* pa0 = pa + r * 8192;
        #pragma unroll
        for (int m = 0; m < 4; ++m) {
            fa[m] = ld16(pa0 + m * 256);
            fb[m] = ld16(pa0 + 4096 + m * 256);
        }
    }
    #pragma unroll
    for (int j = 0; j < 4; ++j)
        *(uint4*)(elds + j * 4096 + t * 16) = rg[j];
    __syncthreads();

    const f32x4 zf = {0.f, 0.f, 0.f, 0.f};
    f32x4 acc[4][4];
    #pragma unroll
    for (int m = 0; m < 4; ++m)
        #pragma unroll
        for (int n = 0; n < 4; ++n) acc[m][n] = zf;

    // E frags for first phase (buf0, local kc = r)
    {
        const char* ep0 = elds + r * 8192 + g * 1024 + lr * 16;
        #pragma unroll
        for (int n = 0; n < 4; ++n) {
            ec[n] = ld16(ep0 + n * 256);
            ed[n] = ld16(ep0 + 4096 + n * 256);
        }
    }

    #pragma unroll
    for (int q = 0; q < 4; ++q) {
        const int buf = (q & 1) * 16384;
        // issue stage loads for quarter q+1 (fly under 2 phases of MFMA, ~1860 cyc)
        if (q < 3) {
            const char* s2 = esrc + (q + 1) * 16384;
            #pragma unroll
            for (int j = 0; j < 4; ++j)
                rg[j] = *(const uint4*)(s2 + j * 4096 + t * 16);
        }
        // head E-frag load for this quarter (q>0; q==0 loaded in prologue)
        if (q > 0) {
            const char* ep = elds + buf + r * 8192 + g * 1024 + lr * 16;
            #pragma unroll
            for (int n = 0; n < 4; ++n) {
                ec[n] = ld16(ep + n * 256);
                ed[n] = ld16(ep + 4096 + n * 256);
            }
        }
        #pragma unroll
        for (int p = 0; p < 2; ++p) {
            const bool lastPhase = (q == 3) && (p == 1);
            // A chunk for the NEXT phase: within quarter -> 2q + (r^1); across -> 2(q+1) + r
            const int kcA = (p == 0) ? (2 * q + (r ^ 1)) : (2 * (q + 1) + r);
            const char* pan = pa + kcA * 8192;
            #pragma unroll
            for (int m = 0; m < 4; ++m) {
                __builtin_amdgcn_s_setprio(1);
                #pragma unroll
                for (int n = 0; n < 4; ++n) {
                    acc[m][n] = __builtin_amdgcn_mfma_f32_16x16x32_f16(fa[m], ec[n], acc[m][n], 0, 0, 0);
                    acc[m][n] = __builtin_amdgcn_mfma_f32_16x16x32_f16(fa[m], ed[n], acc[m][n], 0, 0, 0);
                    acc[m][n] = __builtin_amdgcn_mfma_f32_16x16x32_f16(fb[m], ec[n], acc[m][n], 0, 0, 0);
                }
                __builtin_amdgcn_s_setprio(0);
                // A reload-in-place right after fa[m]/fb[m]'s last use (covered by m+1.. MFMAs)
                if (!lastPhase) {
                    fa[m] = ld16(pan + m * 256);
                    fb[m] = ld16(pan + 4096 + m * 256);
                }
            }
            // E reload for phase p=1 (same buf, local kc = r^1); quarter-head load covers p=0
            if (p == 0) {
                const char* en = elds + buf + (r ^ 1) * 8192 + g * 1024 + lr * 16;
                #pragma unroll
                for (int n = 0; n < 4; ++n) {
                    ec[n] = ld16(en + n * 256);
                    ed[n] = ld16(en + 4096 + n * 256);
                }
            }
        }
        // write staged quarter q+1 into the other buffer (its readers finished in q-1)
        if (q < 3) {
            char* nb = elds + ((q + 1) & 1) * 16384;
            #pragma unroll
            for (int j = 0; j < 4; ++j)
                *(uint4*)(nb + j * 4096 + t * 16) = rg[j];
            __syncthreads();
        }
    }

    // epilogue: per-wave argmin over its 64 codes; waves own disjoint tokens -> no merge
    float eq[4];
    #pragma unroll
    for (int n = 0; n < 4; ++n) eq[n] = esq[bx * 64 + n * 16 + lr];
    #pragma unroll
    for (int m = 0; m < 4; ++m) {
        #pragma unroll
        for (int rr = 0; rr < 4; ++rr) {
            float bv = 3.4e38f; int bi = 0x7fffffff;
            #pragma unroll
            for (int n = 0; n < 4; ++n) {
                const float d = fmaf(-2.0f, acc[m][n][rr], eq[n]);
                const int cidx = bx * 64 + n * 16 + lr;
                if (d < bv) { bv = d; bi = cidx; }
            }
            #pragma unroll
            for (int mk = 1; mk < 16; mk <<= 1) {
                const float ov = __shfl_xor(bv, mk, 16);
                const int   oi = __shfl_xor(bi, mk, 16);
                if (ov < bv || (ov == bv && oi < bi)) { bv = ov; bi = oi; }
            }
            if (lr == 0) {
                const size_t o = (size_t)bx * NTOK + by * 256 + w * 64 + m * 16 + g * 4 + rr;
                cv[o] = bv; ci[o] = bi;
            }
        }
    }

    // ---- decoupled last-arriver merge + gather (rocPRIM-style release/acquire) ----
    __threadfence();                                 // release: cv/ci visible device-wide
    if (t == 0) lastFlag = (atomicAdd(&cnt[by], 1) == 31);
    __syncthreads();
    if (!lastFlag) return;
    __threadfence();                                 // acquire: see all 32 blocks' cv/ci

    {   // merge 32 candidate sets for this by-group's 256 tokens (1 token/thread)
        const int tok = by * 256 + t;
        float bv = cv[tok]; int bi = ci[tok];
        #pragma unroll 8
        for (int s = 1; s < 32; ++s) {
            const float v  = cv[(size_t)s * NTOK + tok];
            const int   i2 = ci[(size_t)s * NTOK + tok];
            if (v < bv || (v == bv && i2 < bi)) { bv = v; bi = i2; }
        }
        sIdx256[t] = bi;
        out[QOFF + tok] = (float)bi;
    }
    __syncthreads();
    // gather quantize: 4 chunks of 64 tokens; fixed c -> 64 contiguous hw (coalesced)
    #pragma unroll
    for (int chunk = 0; chunk < 4; ++chunk) {
        const int n0 = by * 256 + chunk * 64;
        const int b = n0 >> 10, hw0 = n0 & (HW - 1);
        const int i = t & 63, cg = t >> 6;
        const int kidx = sIdx256[chunk * 64 + i];
        const float* er = ew + (size_t)kidx * CDIM;
        float* ob = out + (size_t)b * CDIM * HW + hw0 + i;
        #pragma unroll
        for (int p = 0; p < CDIM / 4; ++p) {
            const int c = cg * 64 + p;
            ob[(size_t)c * HW] = er[c];
        }
    }
}

extern "C" void kernel_launch(void* const* d_in, const int* in_sizes, int n_in,
                              void* d_out, int out_size, void* d_ws, size_t ws_size,
                              hipStream_t stream) {
    const float* x  = (const float*)d_in[0];
    const float* ew = (const float*)d_in[1];
    float* out = (float*)d_out;
    char* ws = (char*)d_ws;

    char*  Aws = ws;                                // 33,554,432 B
    char*  Ews = ws + 33554432;                     //  2,097,152 B
    float* esq = (float*)(ws + 35651584);           //      8,192 B
    float* cvv = (float*)(ws + 35659776);           //  4,194,304 B (32 sets)
    int*   cii = (int*)(ws + 39854080);             //  4,194,304 B
    int*   cnt = (int*)(ws + 44048384);             //        512 B (128 counters)

    prep_kernel<<<1280, 256, 0, stream>>>(x, ew, Aws, Ews, esq, cnt, out);
    vqmm_kernel<<<4096, 256, 0, stream>>>(Aws, Ews, esq, cvv, cii, cnt, ew, out);
}

// Round 19
// 135.213 us; speedup vs baseline: 4.2710x; 4.2710x over previous
//
#include <hip/hip_runtime.h>

// VQ codebook assignment via merged single-accumulator split-f16 MFMA GEMM (K=768 effective).
// R19 = CHAMPION RESTORE (R15, measured 135.15us total / vqmm 105.6us).
// Post-R15 experiments all regressed or nulled:
//   R16 limb-split phases -> live-range stretch -> spill (WRITE 123MB, 127us)
//   R17 product-major MFMA order -> null (compiler already interleaves; 106.8us)
//   R18 last-arriver fused merge (threadfence+atomics) -> 577us disaster
// Structure summary:
//   prep:  fused X-transpose->limb panels + E limbs + esq (1280 blocks)
//   vqmm:  128x64 block tile (4 waves x 64 tokens), quarter-granular double-buffered
//          LDS-E (32KB -> 3 blocks/CU), reload-in-place frags, per-wave rotation,
//          setprio MFMA clusters, XCD-grouped swizzle; per-wave argmin epilogue
//   merge_gather: 32-set candidate merge (s-slice parallel) + coalesced gather
//
// Math (verified R11-R17): xh=f16(64x), xl=f16(64x-xh); eh=f16(2^15 e), el=f16(2^15 e - eh).
//   acc = sum xh*eh + xh*el + xl*eh == 2^21*dot - sum(xl*el)  (dropped ~1e-6 rel)
//   d = 2^21*esq - 2*acc ; argmin preserved.
// Register law (R4/R8/R10/R16): per-SIMD pool 512; 3 waves/SIMD => <=170/wave (~150 used).
// R3: no global_load_lds (kills L2 panel reuse). R18: no device fences in epilogue.

#define CDIM 256
#define KDIM 2048
#define HW   1024
#define NTOK 32768
#define QOFF 8388608
#define LOFF (QOFF + NTOK)

typedef _Float16 f16x8 __attribute__((ext_vector_type(8)));
typedef float    f32x4 __attribute__((ext_vector_type(4)));

__device__ __forceinline__ f16x8 ld16(const char* p) { return *(const f16x8*)(p); }

// ---------------- fused prep: blocks 0..1023 = X transpose, 1024..1279 = E limbs ----------------
__global__ __launch_bounds__(256) void prep_kernel(const float* __restrict__ x,
                                                   const float* __restrict__ ew,
                                                   char* __restrict__ Aws,
                                                   char* __restrict__ Ews,
                                                   float* __restrict__ esq,
                                                   float* __restrict__ out) {
    __shared__ float tile[32][257];
    const int t = threadIdx.x;
    if (blockIdx.x < 1024) {
        const int bid = blockIdx.x;              // 32 b * 8 kc * 4 hwblk
        const int b = bid >> 5;
        const int kc = (bid >> 2) & 7;
        const int c0 = kc * 32;
        const int hw0 = (bid & 3) * 256;
        #pragma unroll 8
        for (int r = 0; r < 32; ++r)
            tile[r][t] = x[((size_t)(b * CDIM + c0 + r) << 10) + hw0 + t];
        __syncthreads();
        union { _Float16 h[32]; uint4 q[4]; } Hb, Lb;
        #pragma unroll 8
        for (int r = 0; r < 32; ++r) {
            const float xs = tile[r][t] * 64.0f;
            const _Float16 hh = (_Float16)xs;
            Hb.h[r] = hh;
            Lb.h[r] = (_Float16)(xs - (float)hh);
        }
        const int tok = b * HW + hw0 + t;
        const int p = tok >> 6, row = tok & 63;
        char* d = Aws + (size_t)p * 65536 + kc * 8192 + row * 16;
        #pragma unroll
        for (int g = 0; g < 4; ++g) {
            *(uint4*)(d + g * 1024)        = Hb.q[g];   // high limb
            *(uint4*)(d + 4096 + g * 1024) = Lb.q[g];   // low limb
        }
    } else {
        const int bid = blockIdx.x - 1024;             // 256 blocks x 8 codes
        const int code = bid * 8 + (t >> 5);
        const int u = t & 31;
        const float4 v0 = *(const float4*)&ew[(size_t)code * CDIM + u * 8];
        const float4 v1 = *(const float4*)&ew[(size_t)code * CDIM + u * 8 + 4];
        float s = v0.x*v0.x + v0.y*v0.y + v0.z*v0.z + v0.w*v0.w
                + v1.x*v1.x + v1.y*v1.y + v1.z*v1.z + v1.w*v1.w;
        #pragma unroll
        for (int m = 16; m >= 1; m >>= 1) s += __shfl_xor(s, m, 32);
        if (u == 0) esq[code] = s * 2097152.0f;        // 2^21 * esq
        const float e[8] = {v0.x, v0.y, v0.z, v0.w, v1.x, v1.y, v1.z, v1.w};
        union { _Float16 h[8]; uint4 q; } H, L;
        #pragma unroll
        for (int j = 0; j < 8; ++j) {
            const float ev = e[j] * 32768.0f;          // 2^15 * e
            const _Float16 hh = (_Float16)ev;
            H.h[j] = hh;
            L.h[j] = (_Float16)(ev - (float)hh);
        }
        const int kc = u >> 2, g = u & 3;
        const int p = code >> 6, row = code & 63;
        char* d = Ews + (size_t)p * 65536 + kc * 8192 + g * 1024 + row * 16;
        *(uint4*)d = H.q;
        *(uint4*)(d + 4096) = L.q;
        if (bid == 0 && t == 0) out[LOFF] = 0.0f;
    }
}

// ---------------- fused MFMA GEMM + argmin: quarter-dbuf async-staged LDS-E ----------------
// Block = 4 waves x 64 tokens (256 tokens) over ONE shared 64-code panel.
__global__ __launch_bounds__(256, 3) void vqmm_kernel(const char* __restrict__ Aws,
                                                      const char* __restrict__ Ews,
                                                      const float* __restrict__ esq,
                                                      float* __restrict__ cv,
                                                      int* __restrict__ ci) {
    __shared__ __align__(16) char elds[32768];   // buf0 | buf1 (16KB each = 2 kc chunks)

    const int t = threadIdx.x;
    const int bid = blockIdx.x;                     // 4096 blocks
    // bijective XCD-grouped swizzle: the 32 code-panels of one token-group share bid%8
    const int by = (bid & 7) | ((bid >> 8) << 3);   // token group 0..127 (256 tokens)
    const int bx = (bid >> 3) & 31;                 // code panel 0..31   (64 codes)
    const int lane = t & 63, w = t >> 6;
    const int g = lane >> 4, lr = lane & 15;
    const int r = (bid + w) & 1;                    // intra-quarter rotation (anti-lockstep)

    const char* pa = Aws + (size_t)(by * 4 + w) * 65536 + g * 1024 + lr * 16;
    const char* esrc = Ews + (size_t)bx * 65536;

    f16x8 fa[4], fb[4], ec[4], ed[4];
    uint4 rg[4];

    // prologue: stage quarter 0 -> buf0; A frags for first phase (kc = r)
    #pragma unroll
    for (int j = 0; j < 4; ++j)
        rg[j] = *(const uint4*)(esrc + j * 4096 + t * 16);
    {
        const char* pa0 = pa + r * 8192;
        #pragma unroll
        for (int m = 0; m < 4; ++m) {
            fa[m] = ld16(pa0 + m * 256);
            fb[m] = ld16(pa0 + 4096 + m * 256);
        }
    }
    #pragma unroll
    for (int j = 0; j < 4; ++j)
        *(uint4*)(elds + j * 4096 + t * 16) = rg[j];
    __syncthreads();

    const f32x4 zf = {0.f, 0.f, 0.f, 0.f};
    f32x4 acc[4][4];
    #pragma unroll
    for (int m = 0; m < 4; ++m)
        #pragma unroll
        for (int n = 0; n < 4; ++n) acc[m][n] = zf;

    // E frags for first phase (buf0, local kc = r)
    {
        const char* ep0 = elds + r * 8192 + g * 1024 + lr * 16;
        #pragma unroll
        for (int n = 0; n < 4; ++n) {
            ec[n] = ld16(ep0 + n * 256);
            ed[n] = ld16(ep0 + 4096 + n * 256);
        }
    }

    #pragma unroll
    for (int q = 0; q < 4; ++q) {
        const int buf = (q & 1) * 16384;
        // issue stage loads for quarter q+1 (fly under 2 phases of MFMA, ~1860 cyc)
        if (q < 3) {
            const char* s2 = esrc + (q + 1) * 16384;
            #pragma unroll
            for (int j = 0; j < 4; ++j)
                rg[j] = *(const uint4*)(s2 + j * 4096 + t * 16);
        }
        // head E-frag load for this quarter (q>0; q==0 loaded in prologue)
        if (q > 0) {
            const char* ep = elds + buf + r * 8192 + g * 1024 + lr * 16;
            #pragma unroll
            for (int n = 0; n < 4; ++n) {
                ec[n] = ld16(ep + n * 256);
                ed[n] = ld16(ep + 4096 + n * 256);
            }
        }
        #pragma unroll
        for (int p = 0; p < 2; ++p) {
            const bool lastPhase = (q == 3) && (p == 1);
            // A chunk for the NEXT phase: within quarter -> 2q + (r^1); across -> 2(q+1) + r
            const int kcA = (p == 0) ? (2 * q + (r ^ 1)) : (2 * (q + 1) + r);
            const char* pan = pa + kcA * 8192;
            #pragma unroll
            for (int m = 0; m < 4; ++m) {
                __builtin_amdgcn_s_setprio(1);
                #pragma unroll
                for (int n = 0; n < 4; ++n) {
                    acc[m][n] = __builtin_amdgcn_mfma_f32_16x16x32_f16(fa[m], ec[n], acc[m][n], 0, 0, 0);
                    acc[m][n] = __builtin_amdgcn_mfma_f32_16x16x32_f16(fa[m], ed[n], acc[m][n], 0, 0, 0);
                    acc[m][n] = __builtin_amdgcn_mfma_f32_16x16x32_f16(fb[m], ec[n], acc[m][n], 0, 0, 0);
                }
                __builtin_amdgcn_s_setprio(0);
                // A reload-in-place right after fa[m]/fb[m]'s last use (covered by m+1.. MFMAs)
                if (!lastPhase) {
                    fa[m] = ld16(pan + m * 256);
                    fb[m] = ld16(pan + 4096 + m * 256);
                }
            }
            // E reload for phase p=1 (same buf, local kc = r^1); quarter-head load covers p=0
            if (p == 0) {
                const char* en = elds + buf + (r ^ 1) * 8192 + g * 1024 + lr * 16;
                #pragma unroll
                for (int n = 0; n < 4; ++n) {
                    ec[n] = ld16(en + n * 256);
                    ed[n] = ld16(en + 4096 + n * 256);
                }
            }
        }
        // write staged quarter q+1 into the other buffer (its readers finished in q-1)
        if (q < 3) {
            char* nb = elds + ((q + 1) & 1) * 16384;
            #pragma unroll
            for (int j = 0; j < 4; ++j)
                *(uint4*)(nb + j * 4096 + t * 16) = rg[j];
            __syncthreads();
        }
    }

    // epilogue: per-wave argmin over its 64 codes; waves own disjoint tokens -> no merge
    float eq[4];
    #pragma unroll
    for (int n = 0; n < 4; ++n) eq[n] = esq[bx * 64 + n * 16 + lr];
    #pragma unroll
    for (int m = 0; m < 4; ++m) {
        #pragma unroll
        for (int rr = 0; rr < 4; ++rr) {
            float bv = 3.4e38f; int bi = 0x7fffffff;
            #pragma unroll
            for (int n = 0; n < 4; ++n) {
                const float d = fmaf(-2.0f, acc[m][n][rr], eq[n]);
                const int cidx = bx * 64 + n * 16 + lr;
                if (d < bv) { bv = d; bi = cidx; }
            }
            #pragma unroll
            for (int mk = 1; mk < 16; mk <<= 1) {
                const float ov = __shfl_xor(bv, mk, 16);
                const int   oi = __shfl_xor(bi, mk, 16);
                if (ov < bv || (ov == bv && oi < bi)) { bv = ov; bi = oi; }
            }
            if (lr == 0) {
                const size_t o = (size_t)bx * NTOK + by * 256 + w * 64 + m * 16 + g * 4 + rr;
                cv[o] = bv; ci[o] = bi;
            }
        }
    }
}

// ---------------- merge 32 candidates + gather quantize (s-slices parallelized) ----------------
__global__ __launch_bounds__(256) void merge_gather_kernel(const float* __restrict__ cv,
                                                           const int* __restrict__ ci,
                                                           const float* __restrict__ ew,
                                                           float* __restrict__ out) {
    __shared__ float redV[256];
    __shared__ int   redI[256];
    __shared__ int   sIdx[64];
    const int t = threadIdx.x;
    const int n0 = blockIdx.x * 64;
    {
        const int tok = n0 + (t & 63);
        const int s0 = (t >> 6) * 8;               // 4 slices of 8 candidate sets
        float bv = 3.4e38f; int bi = 0x7fffffff;
        #pragma unroll
        for (int s = 0; s < 8; ++s) {
            const float v  = cv[(size_t)(s0 + s) * NTOK + tok];
            const int   i2 = ci[(size_t)(s0 + s) * NTOK + tok];
            if (v < bv || (v == bv && i2 < bi)) { bv = v; bi = i2; }
        }
        redV[t] = bv; redI[t] = bi;
    }
    __syncthreads();
    if (t < 64) {
        float bv = redV[t]; int bi = redI[t];
        #pragma unroll
        for (int s = 1; s < 4; ++s) {
            const float v = redV[t + s * 64]; const int i2 = redI[t + s * 64];
            if (v < bv || (v == bv && i2 < bi)) { bv = v; bi = i2; }
        }
        sIdx[t] = bi;
        out[QOFF + n0 + t] = (float)bi;
    }
    __syncthreads();
    const int b = n0 >> 10, hw0 = n0 & (HW - 1);
    const int i = t & 63, cg = t >> 6;
    const int kidx = sIdx[i];
    const float* er = ew + (size_t)kidx * CDIM;
    float* ob = out + (size_t)b * CDIM * HW + hw0 + i;
    #pragma unroll
    for (int p = 0; p < CDIM / 4; ++p) {
        const int c = cg * 64 + p;
        ob[(size_t)c * HW] = er[c];
    }
}

extern "C" void kernel_launch(void* const* d_in, const int* in_sizes, int n_in,
                              void* d_out, int out_size, void* d_ws, size_t ws_size,
                              hipStream_t stream) {
    const float* x  = (const float*)d_in[0];
    const float* ew = (const float*)d_in[1];
    float* out = (float*)d_out;
    char* ws = (char*)d_ws;

    char*  Aws = ws;                                // 33,554,432 B
    char*  Ews = ws + 33554432;                     //  2,097,152 B
    float* esq = (float*)(ws + 35651584);           //      8,192 B
    float* cvv = (float*)(ws + 35659776);           //  4,194,304 B (32 sets)
    int*   cii = (int*)(ws + 39854080);             //  4,194,304 B

    prep_kernel<<<1280, 256, 0, stream>>>(x, ew, Aws, Ews, esq, out);
    vqmm_kernel<<<4096, 256, 0, stream>>>(Aws, Ews, esq, cvv, cii);
    merge_gather_kernel<<<NTOK / 64, 256, 0, stream>>>(cvv, cii, ew, out);
}